// Round 5
// baseline (373.083 us; speedup 1.0000x reference)
//
#include <hip/hip_runtime.h>
#include <hip/hip_bf16.h>
#include <stdint.h>

// Problem: out = x_norm + dropout(relu(LN(x) @ W1) @ W2), B=4,S=2048,D=2048
#define M_DIM 8192   // B*S
#define N_DIM 2048
#define K_DIM 2048

typedef __bf16 bf16x8_t __attribute__((ext_vector_type(8)));
typedef float f32x4_t __attribute__((ext_vector_type(4)));

// ---------------- threefry2x32, JAX partitionable path, key=(0,1) -------------
// bits(j) = o0^o1 of threefry2x32(key=(0,1), ctr=(0, j)); keep iff bits < 0xC0000000.
// Verified: absmax 0.0625 -> mask exact.
__device__ __forceinline__ unsigned tf_rotl(unsigned x, int r) {
  return (x << r) | (x >> (32 - r));
}
__device__ __forceinline__ unsigned threefry_mask_bits(unsigned ctr) {
  unsigned x0 = 0u, x1 = ctr;
  const unsigned ks0 = 0u, ks1 = 1u, ks2 = 0x1BD11BDBu;
  x0 += ks0; x1 += ks1;
#define TFR(r) { x0 += x1; x1 = tf_rotl(x1, (r)); x1 ^= x0; }
  TFR(13) TFR(15) TFR(26) TFR(6)
  x0 += ks1; x1 += ks2 + 1u;
  TFR(17) TFR(29) TFR(16) TFR(24)
  x0 += ks2; x1 += ks0 + 2u;
  TFR(13) TFR(15) TFR(26) TFR(6)
  x0 += ks0; x1 += ks1 + 3u;
  TFR(17) TFR(29) TFR(16) TFR(24)
  x0 += ks1; x1 += ks2 + 4u;
  TFR(13) TFR(15) TFR(26) TFR(6)
  x0 += ks2; x1 += ks0 + 5u;
#undef TFR
  return x0 ^ x1;
}

// ---------------- async global->LDS, 16B per lane -----------------------------
__device__ __forceinline__ void gload_lds16(const __hip_bfloat16* g, unsigned short* l) {
  __builtin_amdgcn_global_load_lds(
      (const __attribute__((address_space(1))) unsigned int*)g,
      (__attribute__((address_space(3))) unsigned int*)l,
      16, 0, 0);
}

// ---------------- W [K][N] fp32 -> Wt [N][K] bf16 -----------------------------
__global__ __launch_bounds__(256) void wt_kernel(
    const float* __restrict__ W1, const float* __restrict__ W2,
    __hip_bfloat16* __restrict__ W1t, __hip_bfloat16* __restrict__ W2t) {
  __shared__ float tile[32][33];
  const float* src = blockIdx.z ? W2 : W1;
  __hip_bfloat16* dst = blockIdx.z ? W2t : W1t;
  int x = blockIdx.x * 32 + threadIdx.x;
  int y = blockIdx.y * 32 + threadIdx.y;
#pragma unroll
  for (int i = 0; i < 32; i += 8)
    tile[threadIdx.y + i][threadIdx.x] = src[(size_t)(y + i) * N_DIM + x];
  __syncthreads();
  int xo = blockIdx.y * 32 + threadIdx.x;
  int yo = blockIdx.x * 32 + threadIdx.y;
#pragma unroll
  for (int i = 0; i < 32; i += 8)
    dst[(size_t)(yo + i) * K_DIM + xo] = __float2bfloat16(tile[threadIdx.x][threadIdx.y + i]);
}

// ---------------- LayerNorm (no affine) -> bf16 -------------------------------
__global__ __launch_bounds__(256) void ln_kernel(const float* __restrict__ X,
                                                 __hip_bfloat16* __restrict__ Xn) {
  const int row = blockIdx.x;
  const float4* xv = (const float4*)(X + (size_t)row * K_DIM);
  float4 v0 = xv[threadIdx.x];
  float4 v1 = xv[threadIdx.x + 256];
  float s  = v0.x + v0.y + v0.z + v0.w + v1.x + v1.y + v1.z + v1.w;
  float ss = v0.x*v0.x + v0.y*v0.y + v0.z*v0.z + v0.w*v0.w
           + v1.x*v1.x + v1.y*v1.y + v1.z*v1.z + v1.w*v1.w;
#pragma unroll
  for (int off = 32; off > 0; off >>= 1) {
    s  += __shfl_xor(s, off);
    ss += __shfl_xor(ss, off);
  }
  __shared__ float rs[4], rss[4];
  const int wave = threadIdx.x >> 6;
  if ((threadIdx.x & 63) == 0) { rs[wave] = s; rss[wave] = ss; }
  __syncthreads();
  float S  = rs[0] + rs[1] + rs[2] + rs[3];
  float SS = rss[0] + rss[1] + rss[2] + rss[3];
  float mean = S * (1.0f / 2048.0f);
  float var  = SS * (1.0f / 2048.0f) - mean * mean;
  float rstd = 1.0f / sqrtf(var + 1e-6f);
  float vv[8] = {v0.x, v0.y, v0.z, v0.w, v1.x, v1.y, v1.z, v1.w};
  unsigned short o[8];
#pragma unroll
  for (int i = 0; i < 8; i++) {
    __hip_bfloat16 b = __float2bfloat16((vv[i] - mean) * rstd);
    o[i] = *(unsigned short*)&b;
  }
  ushort4* dst = (ushort4*)(Xn + (size_t)row * K_DIM);
  dst[threadIdx.x]       = make_ushort4(o[0], o[1], o[2], o[3]);
  dst[threadIdx.x + 256] = make_ushort4(o[4], o[5], o[6], o[7]);
}

// ---------------- 128x256 MFMA GEMM, BK=64, 8-phase counted-vmcnt schedule ----
// Rounds 2-4 post-mortem: 256x256 tile (acc=128 AGPR) under the 512-thread
// 256-reg/wave cap left only 128 VGPRs; allocator was short ~16 regs in EVERY
// schedule variant -> fixed per-tile scratch spill (262 MB writes, identical
// across 3 structures, VGPR pegged at 128). Fix: per-wave output 64x64 ->
// acc[4][4] = 64 AGPR, freeing 64 regs. Tile BM=128 x BN=256, 8 waves (2Mx4N).
// LDS: A 2x16KB + B 2x32KB = 96 KB, double-buffered by K-tile; 1 block/CU.
// LDS rows 64 elems (128 B); 16B-chunk slot s of row r holds global chunk
// s^(r&7) (pre-swizzled global source + swizzled ds_read addr; 0 bank
// conflicts measured with this exact pattern in the 110us 128^2 kernel).
// Per K-tile 4 phases (kk, n-half): {ds_reads; stage; s_barrier; lgkmcnt(0);
// setprio(1); 8 MFMA; setprio(0); s_barrier}. 16 ds_read_b128 + 32 MFMA/tile.
// Staging = 6 gloads/tile, one tile ahead into the OTHER buffer (no intra-tile
// WAR): ph1 A1(t+1), ph2 B01(t+1), ph3 B23(t+1); ph4 stages A0(t+2) into the
// CURRENT buffer (A readers are ph1/ph3, done a barrier earlier) so the
// per-tile wait is vmcnt(1) -- counted, never 0 until the tail drain (t=30).
// Raw s_barrier throughout (__syncthreads would drain vmcnt). Per-acc-element
// MFMA order kk0 then kk1 per tile -> bit-identical numerics to round 0.
// EPI=0: H=relu(A@B)->bf16. EPI=1: out=Xn+dropout(A@B)/0.75.
template <int EPI>
__global__ __launch_bounds__(512, 2) void gemm128x256(
    const __hip_bfloat16* __restrict__ A,
    const __hip_bfloat16* __restrict__ Bt,
    const __hip_bfloat16* __restrict__ Xn,   // EPI=1 residual
    __hip_bfloat16* __restrict__ Hout,       // EPI=0 output
    float* __restrict__ Fout) {              // EPI=1 output
  __shared__ unsigned short As[2][8192];    // 2 x 16 KB (128 rows x 64)
  __shared__ unsigned short Bs[2][16384];   // 2 x 32 KB (256 rows x 64)
  const int tid  = threadIdx.x;
  const int lane = tid & 63;
  const int wave = tid >> 6;      // 0..7
  const int wm = wave >> 2;       // 0..1 (M half of 128)
  const int wn = wave & 3;        // 0..3 (N quarter of 256)

  // XCD-aware swizzle: 512 wgs (divisible by 8) -> XCD x owns all 64 M-tiles
  // of one N-column -> 1 MB B panel L2-resident per XCD.
  const int bid = blockIdx.x;
  const int wg  = (bid & 7) * 64 + (bid >> 3);
  const int mBase = (wg & 63) << 7;   // 64 M-tiles, fastest
  const int nBase = (wg >> 6) << 8;   // 8 N-tiles

  f32x4_t acc[4][4];
#pragma unroll
  for (int i = 0; i < 4; i++)
#pragma unroll
    for (int j = 0; j < 4; j++) acc[i][j] = (f32x4_t){0.f, 0.f, 0.f, 0.f};

  // ---- staging. One gload round = 512 threads x 16B = 64 rows x 128B.
  // Wave w covers 8 rows; lane l: row 8w+(l>>3), source chunk (l&7)^(row&7).
  // A rounds j=0,1 (rows j*64..); B rounds j=0..3.
  const int rowIn = lane >> 3;
  const int csrc  = ((lane & 7) ^ (rowIn & 7)) << 3;   // swizzled src elem offset
  const __hip_bfloat16* aSrcB = A  + (size_t)(mBase + 8 * wave + rowIn) * K_DIM + csrc;
  const __hip_bfloat16* bSrcB = Bt + (size_t)(nBase + 8 * wave + rowIn) * K_DIM + csrc;
  const int dstW = wave << 9;     // shorts; wave-uniform base, HW adds lane*16B

#define STA(b, j, k) \
  gload_lds16(aSrcB + (size_t)((j) * 64) * K_DIM + (k), &As[b][dstW + (j) * 4096]);
#define STB(b, j, k) \
  gload_lds16(bSrcB + (size_t)((j) * 64) * K_DIM + (k), &Bs[b][dstW + (j) * 4096]);

  // ---- fragment read addresses (static swizzle: slot = chunk ^ (row&7))
  const int fr = lane & 15;
  const int fq = lane >> 4;
  const int ck0 = ((fq)     ^ (fr & 7)) << 3;   // kk=0 chunk offset (shorts)
  const int ck1 = ((4 | fq) ^ (fr & 7)) << 3;   // kk=1 chunk offset
  const int aRd = (wm * 64 + fr) * 64;
  const int bRd = (wn * 64 + fr) * 64;

  bf16x8_t aK[4];   // A fragments for current kk (live 2 phases)
  bf16x8_t bb[2];   // B fragments (phase-local)

#define RDA4(B, CK)                                                    \
  aK[0] = *(const bf16x8_t*)&As[B][aRd + 0 * 1024 + (CK)];             \
  aK[1] = *(const bf16x8_t*)&As[B][aRd + 1 * 1024 + (CK)];             \
  aK[2] = *(const bf16x8_t*)&As[B][aRd + 2 * 1024 + (CK)];             \
  aK[3] = *(const bf16x8_t*)&As[B][aRd + 3 * 1024 + (CK)];
#define RDB2(B, NLO, CK)                                               \
  bb[0] = *(const bf16x8_t*)&Bs[B][bRd + ((NLO)) * 1024 + (CK)];       \
  bb[1] = *(const bf16x8_t*)&Bs[B][bRd + ((NLO) + 1) * 1024 + (CK)];

#define MFMA8(NLO)                                                            \
  _Pragma("unroll")                                                           \
  for (int mi = 0; mi < 4; mi++) {                                            \
    _Pragma("unroll")                                                         \
    for (int nj = 0; nj < 2; nj++) {                                          \
      acc[mi][(NLO) + nj] = __builtin_amdgcn_mfma_f32_16x16x32_bf16(          \
          aK[mi], bb[nj], acc[mi][(NLO) + nj], 0, 0, 0);                      \
    }                                                                         \
  }

#define BAR() __builtin_amdgcn_s_barrier()
#define LGKM0() asm volatile("s_waitcnt lgkmcnt(0)" ::: "memory")
#define VMW(n)  asm volatile("s_waitcnt vmcnt(" #n ")" ::: "memory")

  // TILE(T, BUF, OBUF, SE, SP4, VMODE): BUF/OBUF literal 0/1. SE stages tile
  // T+1 (ph1 A1, ph2 B01, ph3 B23 -> OBUF); SP4 stages A0(T+2) -> BUF at ph4.
  // VMODE 0 = VMW(1), 1 = VMW(0) drain, 2 = none.
#define TILE(T, BUF, OBUF, SE, SP4, VMODE)                               \
  {                                                                      \
    /* ph1: kk0, n0-1; stage A1(T+1) */                                  \
    RDA4(BUF, ck0) RDB2(BUF, 0, ck0)                                     \
    if (SE) { STA(OBUF, 1, ((T) + 1) * 64) }                             \
    BAR(); LGKM0();                                                      \
    __builtin_amdgcn_s_setprio(1); MFMA8(0)                              \
    __builtin_amdgcn_s_setprio(0); BAR();                                \
    /* ph2: kk0, n2-3; stage B0,B1(T+1) */                               \
    RDB2(BUF, 2, ck0)                                                    \
    if (SE) { STB(OBUF, 0, ((T) + 1) * 64) STB(OBUF, 1, ((T) + 1) * 64) }\
    BAR(); LGKM0();                                                      \
    __builtin_amdgcn_s_setprio(1); MFMA8(2)                              \
    __builtin_amdgcn_s_setprio(0); BAR();                                \
    /* ph3: kk1, n0-1; stage B2,B3(T+1) */                               \
    RDA4(BUF, ck1) RDB2(BUF, 0, ck1)                                     \
    if (SE) { STB(OBUF, 2, ((T) + 1) * 64) STB(OBUF, 3, ((T) + 1) * 64) }\
    BAR(); LGKM0();                                                      \
    __builtin_amdgcn_s_setprio(1); MFMA8(0)                              \
    __builtin_amdgcn_s_setprio(0); BAR();                                \
    /* ph4: kk1, n2-3; stage A0(T+2) -> current buf (A readers done ph3);*/\
    /* counted wait: all but newest 1 -> tile T+1 fully staged */        \
    RDB2(BUF, 2, ck1)                                                    \
    if (SP4) { STA(BUF, 0, ((T) + 2) * 64) }                             \
    if ((VMODE) == 0) { VMW(1); } else if ((VMODE) == 1) { VMW(0); }     \
    BAR(); LGKM0();                                                      \
    __builtin_amdgcn_s_setprio(1); MFMA8(2)                              \
    __builtin_amdgcn_s_setprio(0); BAR();                                \
  }

  // ---- prologue: tile0 (6 rounds -> buf0) + A0(1) (-> buf1) = 7 gloads.
  // VMW(1): tile0's 6 landed (per wave); BAR makes it collective.
  STA(0, 0, 0) STA(0, 1, 0)
  STB(0, 0, 0) STB(0, 1, 0) STB(0, 2, 0) STB(0, 3, 0)
  STA(1, 0, 64)
  VMW(1);
  BAR();

  // nt = 32 K-tiles. Unrolled by 2 for literal buf. Full pipeline t<30;
  // t=30 stages tile31's remaining 5 rounds then drains; t=31 computes only.
  for (int t = 0; t < 30; t += 2) {
    TILE(t,     0, 1, 1, 1, 0)
    TILE(t + 1, 1, 0, 1, 1, 0)
  }
  TILE(30, 0, 1, 1, 0, 1)
  TILE(31, 1, 0, 0, 0, 2)

#undef TILE
#undef STA
#undef STB
#undef RDA4
#undef RDB2
#undef MFMA8
#undef BAR
#undef LGKM0
#undef VMW

  // epilogue: D row = fq*4 + r, col = fr (m89-verified C/D layout)
  const int mW = mBase + wm * 64 + fq * 4;
  const int nW = nBase + wn * 64 + fr;
#pragma unroll
  for (int mi = 0; mi < 4; mi++) {
#pragma unroll
    for (int nf = 0; nf < 4; nf++) {
      const int n  = nW + nf * 16;
      const int m0 = mW + mi * 16;
#pragma unroll
      for (int r = 0; r < 4; r++) {
        float v = acc[mi][nf][r];
        size_t j = (size_t)(m0 + r) * N_DIM + n;
        if (EPI == 0) {
          Hout[j] = __float2bfloat16(fmaxf(v, 0.0f));
        } else {
          unsigned bits = threefry_mask_bits((unsigned)j);
          float y  = (bits < 0xC0000000u) ? v * (1.0f / 0.75f) : 0.0f;
          Fout[j]  = __bfloat162float(Xn[j]) + y;
        }
      }
    }
  }
}

extern "C" void kernel_launch(void* const* d_in, const int* in_sizes, int n_in,
                              void* d_out, int out_size, void* d_ws, size_t ws_size,
                              hipStream_t stream) {
  (void)in_sizes; (void)n_in; (void)out_size; (void)ws_size;
  const float* X  = (const float*)d_in[0];
  const float* W1 = (const float*)d_in[1];
  const float* W2 = (const float*)d_in[2];
  float* out = (float*)d_out;

  unsigned char* ws = (unsigned char*)d_ws;
  __hip_bfloat16* Xn  = (__hip_bfloat16*)(ws);                       // 32 MB
  __hip_bfloat16* H   = (__hip_bfloat16*)(ws + ((size_t)32 << 20));  // 32 MB
  __hip_bfloat16* W1t = (__hip_bfloat16*)(ws + ((size_t)64 << 20));  //  8 MB
  __hip_bfloat16* W2t = (__hip_bfloat16*)(ws + ((size_t)72 << 20));  //  8 MB

  wt_kernel<<<dim3(64, 64, 2), dim3(32, 8, 1), 0, stream>>>(W1, W2, W1t, W2t);
  ln_kernel<<<M_DIM, 256, 0, stream>>>(X, Xn);
  gemm128x256<0><<<dim3(512, 1, 1), dim3(512, 1, 1), 0, stream>>>(Xn, W1t, nullptr, H, nullptr);
  gemm128x256<1><<<dim3(512, 1, 1), dim3(512, 1, 1), 0, stream>>>(H, W2t, Xn, nullptr, out);
}

// Round 6
// 315.583 us; speedup vs baseline: 1.1822x; 1.1822x over previous
//
#include <hip/hip_runtime.h>
#include <hip/hip_bf16.h>
#include <stdint.h>

// Problem: out = x_norm + dropout(relu(LN(x) @ W1) @ W2), B=4,S=2048,D=2048
#define M_DIM 8192   // B*S
#define N_DIM 2048
#define K_DIM 2048

typedef __bf16 bf16x8_t __attribute__((ext_vector_type(8)));
typedef float f32x4_t __attribute__((ext_vector_type(4)));

// ---------------- threefry2x32, JAX partitionable path, key=(0,1) -------------
// bits(j) = o0^o1 of threefry2x32(key=(0,1), ctr=(0, j)); keep iff bits < 0xC0000000.
// Verified: absmax 0.0625 -> mask exact.
__device__ __forceinline__ unsigned tf_rotl(unsigned x, int r) {
  return (x << r) | (x >> (32 - r));
}
__device__ __forceinline__ unsigned threefry_mask_bits(unsigned ctr) {
  unsigned x0 = 0u, x1 = ctr;
  const unsigned ks0 = 0u, ks1 = 1u, ks2 = 0x1BD11BDBu;
  x0 += ks0; x1 += ks1;
#define TFR(r) { x0 += x1; x1 = tf_rotl(x1, (r)); x1 ^= x0; }
  TFR(13) TFR(15) TFR(26) TFR(6)
  x0 += ks1; x1 += ks2 + 1u;
  TFR(17) TFR(29) TFR(16) TFR(24)
  x0 += ks2; x1 += ks0 + 2u;
  TFR(13) TFR(15) TFR(26) TFR(6)
  x0 += ks0; x1 += ks1 + 3u;
  TFR(17) TFR(29) TFR(16) TFR(24)
  x0 += ks1; x1 += ks2 + 4u;
  TFR(13) TFR(15) TFR(26) TFR(6)
  x0 += ks2; x1 += ks0 + 5u;
#undef TFR
  return x0 ^ x1;
}

// ---------------- async global->LDS, 16B per lane -----------------------------
__device__ __forceinline__ void gload_lds16(const __hip_bfloat16* g, unsigned short* l) {
  __builtin_amdgcn_global_load_lds(
      (const __attribute__((address_space(1))) unsigned int*)g,
      (__attribute__((address_space(3))) unsigned int*)l,
      16, 0, 0);
}

// ---------------- W [K][N] fp32 -> Wt [N][K] bf16 -----------------------------
__global__ __launch_bounds__(256) void wt_kernel(
    const float* __restrict__ W1, const float* __restrict__ W2,
    __hip_bfloat16* __restrict__ W1t, __hip_bfloat16* __restrict__ W2t) {
  __shared__ float tile[32][33];
  const float* src = blockIdx.z ? W2 : W1;
  __hip_bfloat16* dst = blockIdx.z ? W2t : W1t;
  int x = blockIdx.x * 32 + threadIdx.x;
  int y = blockIdx.y * 32 + threadIdx.y;
#pragma unroll
  for (int i = 0; i < 32; i += 8)
    tile[threadIdx.y + i][threadIdx.x] = src[(size_t)(y + i) * N_DIM + x];
  __syncthreads();
  int xo = blockIdx.y * 32 + threadIdx.x;
  int yo = blockIdx.x * 32 + threadIdx.y;
#pragma unroll
  for (int i = 0; i < 32; i += 8)
    dst[(size_t)(yo + i) * K_DIM + xo] = __float2bfloat16(tile[threadIdx.x][threadIdx.y + i]);
}

// ---------------- LayerNorm (no affine) -> bf16 -------------------------------
__global__ __launch_bounds__(256) void ln_kernel(const float* __restrict__ X,
                                                 __hip_bfloat16* __restrict__ Xn) {
  const int row = blockIdx.x;
  const float4* xv = (const float4*)(X + (size_t)row * K_DIM);
  float4 v0 = xv[threadIdx.x];
  float4 v1 = xv[threadIdx.x + 256];
  float s  = v0.x + v0.y + v0.z + v0.w + v1.x + v1.y + v1.z + v1.w;
  float ss = v0.x*v0.x + v0.y*v0.y + v0.z*v0.z + v0.w*v0.w
           + v1.x*v1.x + v1.y*v1.y + v1.z*v1.z + v1.w*v1.w;
#pragma unroll
  for (int off = 32; off > 0; off >>= 1) {
    s  += __shfl_xor(s, off);
    ss += __shfl_xor(ss, off);
  }
  __shared__ float rs[4], rss[4];
  const int wave = threadIdx.x >> 6;
  if ((threadIdx.x & 63) == 0) { rs[wave] = s; rss[wave] = ss; }
  __syncthreads();
  float S  = rs[0] + rs[1] + rs[2] + rs[3];
  float SS = rss[0] + rss[1] + rss[2] + rss[3];
  float mean = S * (1.0f / 2048.0f);
  float var  = SS * (1.0f / 2048.0f) - mean * mean;
  float rstd = 1.0f / sqrtf(var + 1e-6f);
  float vv[8] = {v0.x, v0.y, v0.z, v0.w, v1.x, v1.y, v1.z, v1.w};
  unsigned short o[8];
#pragma unroll
  for (int i = 0; i < 8; i++) {
    __hip_bfloat16 b = __float2bfloat16((vv[i] - mean) * rstd);
    o[i] = *(unsigned short*)&b;
  }
  ushort4* dst = (ushort4*)(Xn + (size_t)row * K_DIM);
  dst[threadIdx.x]       = make_ushort4(o[0], o[1], o[2], o[3]);
  dst[threadIdx.x + 256] = make_ushort4(o[4], o[5], o[6], o[7]);
}

// ---------------- 128x128 MFMA GEMM, BK=64 dbuf, counted-vmcnt pipeline -------
// This is the verified round-0 kernel (110us/GEMM: tile, swizzle, COMPUTE,
// epilogue identical, 0 bank conflicts, bit-identical numerics) with ONE
// change: the per-K-step __syncthreads (which drains vmcnt(0) -- the
// documented ~20% all-wave stall of this structure) is replaced by a 3-deep
// counted pipeline:
//   per tile t (K-64, buf = t&1):
//     COMPUTE(buf)            // compiler-interleaved ds_read+MFMA, as before
//     s_barrier               // all waves' reads of buf complete (MFMA-consumed)
//     STAGE(buf, 64*(t+2))    // overwrite just-freed buf: strict WAR safety
//     s_waitcnt vmcnt(8)      // only the stage just issued may remain in
//     s_barrier               //   flight => tile t+1's buffer fully landed
// Stage flight time = one full tile (~500cy) >> HBM latency. Drain vmcnt(0)
// only at tile 30; tile 31 computes only. Raw s_barrier throughout.
// EPI=0: H=relu(A@B)->bf16. EPI=1: out=Xn+dropout/0.75.
template <int EPI>
__global__ __launch_bounds__(256) void gemm128(
    const __hip_bfloat16* __restrict__ A,
    const __hip_bfloat16* __restrict__ Bt,
    const __hip_bfloat16* __restrict__ Xn,   // EPI=1 residual
    __hip_bfloat16* __restrict__ Hout,       // EPI=0 output
    float* __restrict__ Fout) {              // EPI=1 output
  __shared__ unsigned short As[2][128 * 64];  // 32 KB
  __shared__ unsigned short Bs[2][128 * 64];  // 32 KB
  const int tid  = threadIdx.x;
  const int lane = tid & 63;
  const int wave = tid >> 6;
  const int wm = wave >> 1, wn = wave & 1;
  // grid: x walks M (fastest) -> consecutive blocks share the B panel in L2.
  const int mBase = blockIdx.x * 128;
  const int nBase = blockIdx.y * 128;

  f32x4_t acc[4][4];
#pragma unroll
  for (int i = 0; i < 4; i++)
#pragma unroll
    for (int j = 0; j < 4; j++) acc[i][j] = (f32x4_t){0.f, 0.f, 0.f, 0.f};

  // ---- staging: 16 KB per matrix per stage = 16 chunks of 1 KB (8 rows x 128B).
  // wave w loads chunks {w, w+4, w+8, w+12} of A and of B (8 gloads/stage).
  // lane l covers row 8*ca + (l>>3), source k-chunk (l&7)^((l>>3)&7) (swizzle).
  const int rowIn  = lane >> 3;                       // 0..7 within chunk
  const int csrc   = ((lane & 7) ^ (rowIn & 7)) << 3; // swizzled src k-elem offset
  const __hip_bfloat16* aSrc[4];
  const __hip_bfloat16* bSrc[4];
  int sDst[4];
#pragma unroll
  for (int j = 0; j < 4; j++) {
    const int ca = wave + 4 * j;                      // chunk index 0..15
    aSrc[j] = A  + (size_t)(mBase + 8 * ca + rowIn) * K_DIM + csrc;
    bSrc[j] = Bt + (size_t)(nBase + 8 * ca + rowIn) * K_DIM + csrc;
    sDst[j] = ca * 512;                               // shorts: 1KB per chunk
  }

  // ---- fragment read addresses (static swizzle: row&7 == fr&7)
  const int fr = lane & 15;
  const int fq = lane >> 4;
  const int sw = fr & 7;
  const int cA0 = (fq ^ sw) * 8;          // kk=0 chunk offset (shorts)
  const int cA1 = ((4 | fq) ^ sw) * 8;    // kk=1 chunk offset
  const int rowOffA = (wm * 64 + fr) * 64;
  const int rowOffB = (wn * 64 + fr) * 64;

#define STAGE(buf, k0)                                        \
  {                                                           \
    _Pragma("unroll")                                         \
    for (int j = 0; j < 4; j++) {                             \
      gload_lds16(aSrc[j] + (k0), &As[buf][sDst[j]]);         \
      gload_lds16(bSrc[j] + (k0), &Bs[buf][sDst[j]]);         \
    }                                                         \
  }

#define COMPUTE_HALF(buf, cOff)                                                 \
  {                                                                             \
    bf16x8_t af[4], bfr[4];                                                     \
    _Pragma("unroll")                                                           \
    for (int i = 0; i < 4; i++) af[i]  = *(const bf16x8_t*)(&As[buf][rowOffA + i * 1024 + (cOff)]); \
    _Pragma("unroll")                                                           \
    for (int i = 0; i < 4; i++) bfr[i] = *(const bf16x8_t*)(&Bs[buf][rowOffB + i * 1024 + (cOff)]); \
    _Pragma("unroll")                                                           \
    for (int mi = 0; mi < 4; mi++)                                              \
      _Pragma("unroll")                                                         \
      for (int ni = 0; ni < 4; ni++)                                            \
        acc[mi][ni] = __builtin_amdgcn_mfma_f32_16x16x32_bf16(af[mi], bfr[ni], acc[mi][ni], 0, 0, 0); \
  }
#define COMPUTE(buf) { COMPUTE_HALF(buf, cA0) COMPUTE_HALF(buf, cA1) }

#define BAR() __builtin_amdgcn_s_barrier()
#define VMW(n)  asm volatile("s_waitcnt vmcnt(" #n ")" ::: "memory")

  // TSTEP(BUF, STG, KNEXT, VMODE): one K-64 tile on buffer BUF (literal).
  // STG: stage tile t+2 at offset KNEXT into BUF. VMODE 0 = VMW(8) counted,
  // 1 = VMW(0) drain (tile 30), 2 = none (tile 31).
#define TSTEP(BUF, STG, KNEXT, VMODE)                                    \
  {                                                                      \
    COMPUTE(BUF)                                                         \
    BAR();                        /* all waves done reading BUF */       \
    if (STG) { STAGE(BUF, KNEXT) }                                       \
    if ((VMODE) == 0) { VMW(8); } else if ((VMODE) == 1) { VMW(0); }     \
    if ((VMODE) != 2) { BAR(); }  /* next buffer published */            \
  }

  // ---- prologue: tiles 0 and 1 staged; VMW(8) -> tile0's 8 gloads landed.
  STAGE(0, 0)
  STAGE(1, 64)
  VMW(8);
  BAR();

  // 32 K-tiles. Pairs (t, t+1) with literal buffers; tile t stages t+2.
  // t=0..29 full pipeline; t=30 drains (stage(31) outstanding); t=31 compute only.
  for (int k0 = 0; k0 < 1920; k0 += 128) {
    TSTEP(0, 1, k0 + 128, 0)
    TSTEP(1, 1, k0 + 192, 0)
  }
  TSTEP(0, 0, 0, 1)
  TSTEP(1, 0, 0, 2)

#undef TSTEP
#undef STAGE
#undef COMPUTE
#undef COMPUTE_HALF
#undef BAR
#undef VMW

  // epilogue: D row = fq*4 + reg, col = fr (m89-verified C/D layout)
  const int mRow = mBase + wm * 64;
  const int nCol = nBase + wn * 64;
#pragma unroll
  for (int mi = 0; mi < 4; mi++) {
#pragma unroll
    for (int ni = 0; ni < 4; ni++) {
      const int n  = nCol + ni * 16 + fr;
      const int m0 = mRow + mi * 16 + fq * 4;
#pragma unroll
      for (int r = 0; r < 4; r++) {
        float v = acc[mi][ni][r];
        size_t j = (size_t)(m0 + r) * N_DIM + n;
        if (EPI == 0) {
          Hout[j] = __float2bfloat16(fmaxf(v, 0.0f));
        } else {
          unsigned bits = threefry_mask_bits((unsigned)j);
          float y  = (bits < 0xC0000000u) ? v * (1.0f / 0.75f) : 0.0f;
          Fout[j]  = __bfloat162float(Xn[j]) + y;
        }
      }
    }
  }
}

extern "C" void kernel_launch(void* const* d_in, const int* in_sizes, int n_in,
                              void* d_out, int out_size, void* d_ws, size_t ws_size,
                              hipStream_t stream) {
  (void)in_sizes; (void)n_in; (void)out_size; (void)ws_size;
  const float* X  = (const float*)d_in[0];
  const float* W1 = (const float*)d_in[1];
  const float* W2 = (const float*)d_in[2];
  float* out = (float*)d_out;

  unsigned char* ws = (unsigned char*)d_ws;
  __hip_bfloat16* Xn  = (__hip_bfloat16*)(ws);                       // 32 MB
  __hip_bfloat16* H   = (__hip_bfloat16*)(ws + ((size_t)32 << 20));  // 32 MB
  __hip_bfloat16* W1t = (__hip_bfloat16*)(ws + ((size_t)64 << 20));  //  8 MB
  __hip_bfloat16* W2t = (__hip_bfloat16*)(ws + ((size_t)72 << 20));  //  8 MB

  wt_kernel<<<dim3(64, 64, 2), dim3(32, 8, 1), 0, stream>>>(W1, W2, W1t, W2t);
  ln_kernel<<<M_DIM, 256, 0, stream>>>(X, Xn);
  gemm128<0><<<dim3(M_DIM / 128, N_DIM / 128), 256, 0, stream>>>(Xn, W1t, nullptr, H, nullptr);
  gemm128<1><<<dim3(M_DIM / 128, N_DIM / 128), 256, 0, stream>>>(H, W2t, Xn, nullptr, out);
}